// Round 16
// baseline (315.193 us; speedup 1.0000x reference)
//
#include <hip/hip_runtime.h>
#include <hip/hip_bf16.h>
#include <hip/hip_fp16.h>

typedef _Float16 v8h __attribute__((ext_vector_type(8)));
typedef float v4f __attribute__((ext_vector_type(4)));

#define NB 64            // histogram/scatter chunk blocks
#define HWORDS 12544     // 50176 B static LDS: u32 words per N-half (halfN/2 <= HWORDS)

// ---------------- D1: LDS-private histogram + x0->fp16 convert + W1/W2/W3 frag swizzle ----------------
// Blocks [0,NB): block b histograms its edge chunk into hist16[b][d] (two N-halves, packed
// 16-bit counters in 32-bit LDS atomics — per-half counts < 65536 so no carry crossing).
// Blocks [NB, NB+convBlocks): Xh = fp16(x0), 8 elems/thread.
// Blocks [NB+convBlocks, +192): repack W1,W2,W3 into MFMA B-fragment order.
__global__ __launch_bounds__(256) void hist_conv(const int* __restrict__ dst,
                                                 unsigned* __restrict__ hist32,
                                                 int E, int halfN, int chunk,
                                                 const float* __restrict__ X0,
                                                 __half* __restrict__ Xh, int nElem8,
                                                 int convBlocks,
                                                 const float* __restrict__ W1,
                                                 const float* __restrict__ W2,
                                                 const float* __restrict__ W3,
                                                 __half* __restrict__ wfrag) {
    __shared__ unsigned sh[HWORDS];
    int tid = threadIdx.x;
    if (blockIdx.x < NB) {
        int b = blockIdx.x;
        int e0 = b * chunk, e1 = min(e0 + chunk, E);
        int hw = halfN >> 1;
        for (int h = 0; h < 2; ++h) {
            for (int j = tid; j < hw; j += 256) sh[j] = 0;
            __syncthreads();
            int base = h * halfN;
            for (int e = e0 + tid; e < e1; e += 256) {
                int rel = dst[e] - base;
                if (rel >= 0 && rel < halfN)
                    atomicAdd(&sh[rel >> 1], 1u << ((rel & 1) * 16));
            }
            __syncthreads();
            unsigned* outp = hist32 + (size_t)b * halfN + h * hw;
            for (int j = tid; j < hw; j += 256) outp[j] = sh[j];
            __syncthreads();
        }
        return;
    }
    int bb = blockIdx.x - NB;
    if (bb < convBlocks) {
        int i = bb * 256 + tid;
        if (i < nElem8) {
            float4 v0 = ((const float4*)X0)[i * 2];
            float4 v1 = ((const float4*)X0)[i * 2 + 1];
            auto pk = [](float x, float y) { __half2 h = __floats2half2_rn(x, y); return *(unsigned int*)&h; };
            uint4 q = make_uint4(pk(v0.x, v0.y), pk(v0.z, v0.w), pk(v1.x, v1.y), pk(v1.z, v1.w));
            ((uint4*)Xh)[i] = q;
        }
        return;
    }
    int o = (bb - convBlocks) * 256 + tid;       // 3*16384 elements
    int w = o >> 14, r = o & 16383;
    const float* Ws = (w == 0) ? W1 : (w == 1) ? W2 : W3;
    int k = r >> 7, ncol = r & 127;
    int c = ncol >> 4, nl = ncol & 15;
    int s = k >> 5, quad = (k >> 3) & 3, j = k & 7;
    int di = ((c * 4 + s) * 64 + quad * 16 + nl) * 8 + j;
    wfrag[(size_t)w * 16384 + di] = __float2half_rn(Ws[r]);
}

// ---------------- D2: layer-1 MFMA GEMM (unscaled) + scanA (hist-sum + per-block scan) ----------------
// Blocks [0, gemmBlocks): H1 = fp16(Xh @ W1) via mfma_f32_16x16x32_f16, no dinv scale.
// Blocks [gemmBlocks, +nbN): cnt[i] = sum_b hist16[b][i]; inclusive scan of (cnt+1) per block.
__global__ __launch_bounds__(256) void gemm1_scanA(const __half* __restrict__ Xh,
                                                   const __half* __restrict__ wfrag,
                                                   __half* __restrict__ H, int Nrows,
                                                   int gemmBlocks,
                                                   const unsigned short* __restrict__ hist16,
                                                   int halfN2,
                                                   int* __restrict__ cnt, int* __restrict__ tmp,
                                                   int* __restrict__ bsum, int n) {
    __shared__ int s[256];
    int tid = threadIdx.x;
    if (blockIdx.x < gemmBlocks) {
        int l = tid & 63;
        int wid = tid >> 6;
        int rowbase = blockIdx.x * 64 + wid * 16;
        int quad = l >> 4;
        int nn = l & 15;
        int ra = rowbase + (l & 15);
        if (ra > Nrows - 1) ra = Nrows - 1;
        const v8h* Xf = (const v8h*)(Xh + (size_t)ra * 128);
        v8h a0 = Xf[0 * 4 + quad];
        v8h a1 = Xf[1 * 4 + quad];
        v8h a2 = Xf[2 * 4 + quad];
        v8h a3 = Xf[3 * 4 + quad];
        const v8h* Wf = (const v8h*)wfrag;
        v4f acc[8] = {};
#pragma unroll
        for (int c = 0; c < 8; ++c) {
            v8h b0 = Wf[(c * 4 + 0) * 64 + l];
            v8h b1 = Wf[(c * 4 + 1) * 64 + l];
            v8h b2 = Wf[(c * 4 + 2) * 64 + l];
            v8h b3 = Wf[(c * 4 + 3) * 64 + l];
            acc[c] = __builtin_amdgcn_mfma_f32_16x16x32_f16(a0, b0, acc[c], 0, 0, 0);
            acc[c] = __builtin_amdgcn_mfma_f32_16x16x32_f16(a1, b1, acc[c], 0, 0, 0);
            acc[c] = __builtin_amdgcn_mfma_f32_16x16x32_f16(a2, b2, acc[c], 0, 0, 0);
            acc[c] = __builtin_amdgcn_mfma_f32_16x16x32_f16(a3, b3, acc[c], 0, 0, 0);
        }
#pragma unroll
        for (int reg = 0; reg < 4; ++reg) {
            int gr = rowbase + quad * 4 + reg;
            if (gr < Nrows) {
#pragma unroll
                for (int c = 0; c < 8; ++c)
                    H[(size_t)gr * 128 + c * 16 + nn] = __float2half_rn(acc[c][reg]);
            }
        }
        return;
    }
    int blk = blockIdx.x - gemmBlocks;
    int i = blk * 256 + tid;
    int v = 0;
    if (i < n) {
        int sum = 0;
        for (int b = 0; b < NB; ++b) sum += hist16[(size_t)b * halfN2 + i];
        cnt[i] = sum;
        v = sum + 1;
    }
    s[tid] = v;
    __syncthreads();
    for (int off = 1; off < 256; off <<= 1) {
        int x = (tid >= off) ? s[tid - off] : 0;
        __syncthreads();
        s[tid] += x;
        __syncthreads();
    }
    if (i < n) tmp[i] = s[tid];
    if (tid == 255) bsum[blk] = s[255];
}

// ---------------- D3: scanB + vertical prefix of hist (in place) ----------------
// rowptr/dinv/self-loop as before; then hist16[b][i] := sum_{b'<b} hist16[b'][i]
// (exclusive), giving each scatter block its starting rank per node.
__global__ void scanB(const int* __restrict__ tmp, const int* __restrict__ bsum,
                      const int* __restrict__ cnt, int* __restrict__ rowptr,
                      float* __restrict__ dinv, int* __restrict__ col, int n, int nb,
                      unsigned short* __restrict__ hist16, int halfN2) {
    __shared__ int p[256];
    int t = threadIdx.x;
    p[t] = (t < nb) ? bsum[t] : 0;
    __syncthreads();
    for (int off = 1; off < 256; off <<= 1) {
        int x = (t >= off) ? p[t - off] : 0;
        __syncthreads();
        p[t] += x;
        __syncthreads();
    }
    int prefix = (blockIdx.x == 0) ? 0 : p[blockIdx.x - 1];
    int i = blockIdx.x * 256 + t;
    if (i < n) {
        int inc = tmp[i] + prefix;
        rowptr[i + 1] = inc;
        int c1 = cnt[i] + 1;
        dinv[i] = rsqrtf((float)c1);
        col[inc - c1] = i;                     // self-loop occupies slot 0 of row i
        if (i == 0) rowptr[0] = 0;
        unsigned run = 0;
        for (int b = 0; b < NB; ++b) {
            size_t ix = (size_t)b * halfN2 + i;
            unsigned short tv = hist16[ix];
            hist16[ix] = (unsigned short)run;
            run += tv;
        }
    }
}

// ---------------- D4: atomic-free-global scatter fill (LDS cursors only) ----------------
// Block b reloads its prefix row into LDS cursors (packed 16-bit), then for each edge
// in its chunk: rank = LDS fetch-add, col[rowptr[d]+1+rank] = src[e].
__global__ __launch_bounds__(256) void scatter_fill(const int* __restrict__ src,
                                                    const int* __restrict__ dst,
                                                    const unsigned* __restrict__ hist32,
                                                    const int* __restrict__ rowptr,
                                                    int* __restrict__ col,
                                                    int E, int halfN, int chunk) {
    __shared__ unsigned sh[HWORDS];
    int tid = threadIdx.x;
    int b = blockIdx.x;
    int e0 = b * chunk, e1 = min(e0 + chunk, E);
    int hw = halfN >> 1;
    for (int h = 0; h < 2; ++h) {
        const unsigned* in = hist32 + (size_t)b * halfN + h * hw;
        for (int j = tid; j < hw; j += 256) sh[j] = in[j];
        __syncthreads();
        int base = h * halfN;
        for (int e = e0 + tid; e < e1; e += 256) {
            int d = dst[e];
            int rel = d - base;
            if (rel >= 0 && rel < halfN) {
                unsigned old = atomicAdd(&sh[rel >> 1], 1u << ((rel & 1) * 16));
                int rank = (old >> ((rel & 1) * 16)) & 0xffff;
                col[rowptr[d] + 1 + rank] = src[e];
            }
        }
        __syncthreads();
    }
}

// ---------------- layer-1 aggregation: x̃1 = dinv ⊙ relu(dinv_n·Σ dinv_s·H1[s] + b) ----------------
__global__ __launch_bounds__(256) void agg_h(const __half* __restrict__ H,
                                             const float* __restrict__ dinv,
                                             const int* __restrict__ rowptr,
                                             const int* __restrict__ col,
                                             const float* __restrict__ bias,
                                             __half* __restrict__ out, int n) {
    int node = blockIdx.x * 16 + (threadIdx.x >> 4);
    int t = (threadIdx.x & 15) * 8;
    if (node >= n) return;
    int beg = rowptr[node], end = rowptr[node + 1];
    float a[8] = {};
    int k = beg;
    for (; k + 4 <= end; k += 4) {
        int s0 = col[k], s1 = col[k + 1], s2 = col[k + 2], s3 = col[k + 3];
        float w0 = dinv[s0], w1 = dinv[s1], w2 = dinv[s2], w3 = dinv[s3];
        uint4 r0 = *(const uint4*)&H[(size_t)s0 * 128 + t];
        uint4 r1 = *(const uint4*)&H[(size_t)s1 * 128 + t];
        uint4 r2 = *(const uint4*)&H[(size_t)s2 * 128 + t];
        uint4 r3 = *(const uint4*)&H[(size_t)s3 * 128 + t];
        const __half2* h0 = (const __half2*)&r0;
        const __half2* h1 = (const __half2*)&r1;
        const __half2* h2 = (const __half2*)&r2;
        const __half2* h3 = (const __half2*)&r3;
#pragma unroll
        for (int m = 0; m < 4; ++m) {
            float2 f0 = __half22float2(h0[m]);
            float2 f1 = __half22float2(h1[m]);
            float2 f2 = __half22float2(h2[m]);
            float2 f3 = __half22float2(h3[m]);
            a[2 * m]     += f0.x * w0 + f1.x * w1 + f2.x * w2 + f3.x * w3;
            a[2 * m + 1] += f0.y * w0 + f1.y * w1 + f2.y * w2 + f3.y * w3;
        }
    }
    for (; k < end; ++k) {
        int s0 = col[k];
        float w0 = dinv[s0];
        uint4 r0 = *(const uint4*)&H[(size_t)s0 * 128 + t];
        const __half2* h0 = (const __half2*)&r0;
#pragma unroll
        for (int m = 0; m < 4; ++m) {
            float2 f0 = __half22float2(h0[m]);
            a[2 * m] += f0.x * w0;
            a[2 * m + 1] += f0.y * w0;
        }
    }
    float dn = dinv[node];
    float4 b0 = *(const float4*)&bias[t];
    float4 b1 = *(const float4*)&bias[t + 4];
    float r0 = fmaxf(a[0] * dn + b0.x, 0.f) * dn;
    float r1 = fmaxf(a[1] * dn + b0.y, 0.f) * dn;
    float r2 = fmaxf(a[2] * dn + b0.z, 0.f) * dn;
    float r3 = fmaxf(a[3] * dn + b0.w, 0.f) * dn;
    float r4 = fmaxf(a[4] * dn + b1.x, 0.f) * dn;
    float r5 = fmaxf(a[5] * dn + b1.y, 0.f) * dn;
    float r6 = fmaxf(a[6] * dn + b1.z, 0.f) * dn;
    float r7 = fmaxf(a[7] * dn + b1.w, 0.f) * dn;
    auto pk = [](float x, float y) { __half2 h = __floats2half2_rn(x, y); return *(unsigned int*)&h; };
    uint4 o = make_uint4(pk(r0, r1), pk(r2, r3), pk(r4, r5), pk(r6, r7));
    *(uint4*)&out[(size_t)node * 128 + t] = o;
}

// ---------------- FUSED layer (2,3): Out = post( (dinv ⊙ Â·Xs) @ W + b ) ----------------
__global__ __launch_bounds__(256) void agg_gemm(const __half* __restrict__ Xs,
                                                const float* __restrict__ dinv,
                                                const int* __restrict__ rowptr,
                                                const int* __restrict__ col,
                                                const __half* __restrict__ wfrag,
                                                const float* __restrict__ bias,
                                                __half* __restrict__ Out,
                                                int n, int finalLayer) {
    __shared__ __align__(16) _Float16 y[64][136];
    int tid = threadIdx.x;
    int rowbase = blockIdx.x * 64;
    {
        int sub = tid >> 4;
        int t = (tid & 15) * 8;
        for (int g = 0; g < 4; ++g) {
            int rr = g * 16 + sub;
            int node = rowbase + rr;
            float a[8] = {};
            if (node < n) {
                int beg = rowptr[node], end = rowptr[node + 1];
                int k = beg;
                for (; k + 4 <= end; k += 4) {
                    int s0 = col[k], s1 = col[k + 1], s2 = col[k + 2], s3 = col[k + 3];
                    uint4 r0 = *(const uint4*)&Xs[(size_t)s0 * 128 + t];
                    uint4 r1 = *(const uint4*)&Xs[(size_t)s1 * 128 + t];
                    uint4 r2 = *(const uint4*)&Xs[(size_t)s2 * 128 + t];
                    uint4 r3 = *(const uint4*)&Xs[(size_t)s3 * 128 + t];
                    const __half2* h0 = (const __half2*)&r0;
                    const __half2* h1 = (const __half2*)&r1;
                    const __half2* h2 = (const __half2*)&r2;
                    const __half2* h3 = (const __half2*)&r3;
#pragma unroll
                    for (int m = 0; m < 4; ++m) {
                        float2 f0 = __half22float2(h0[m]);
                        float2 f1 = __half22float2(h1[m]);
                        float2 f2 = __half22float2(h2[m]);
                        float2 f3 = __half22float2(h3[m]);
                        a[2 * m]     += (f0.x + f1.x) + (f2.x + f3.x);
                        a[2 * m + 1] += (f0.y + f1.y) + (f2.y + f3.y);
                    }
                }
                for (; k < end; ++k) {
                    uint4 r0 = *(const uint4*)&Xs[(size_t)col[k] * 128 + t];
                    const __half2* h0 = (const __half2*)&r0;
#pragma unroll
                    for (int m = 0; m < 4; ++m) {
                        float2 f0 = __half22float2(h0[m]);
                        a[2 * m] += f0.x;
                        a[2 * m + 1] += f0.y;
                    }
                }
                float dn = dinv[node];
#pragma unroll
                for (int m = 0; m < 8; ++m) a[m] *= dn;
            }
            v8h yv;
#pragma unroll
            for (int m = 0; m < 8; ++m) yv[m] = (_Float16)a[m];
            *(v8h*)&y[rr][t] = yv;
        }
    }
    __syncthreads();
    int l = tid & 63;
    int wid = tid >> 6;
    int rb = wid * 16;
    int quad = l >> 4;
    int nn = l & 15;
    v8h a0 = *(const v8h*)&y[rb + nn][0 * 32 + quad * 8];
    v8h a1 = *(const v8h*)&y[rb + nn][1 * 32 + quad * 8];
    v8h a2 = *(const v8h*)&y[rb + nn][2 * 32 + quad * 8];
    v8h a3 = *(const v8h*)&y[rb + nn][3 * 32 + quad * 8];
    const v8h* Wf = (const v8h*)wfrag;
    v4f acc[8] = {};
#pragma unroll
    for (int c = 0; c < 8; ++c) {
        v8h b0 = Wf[(c * 4 + 0) * 64 + l];
        v8h b1 = Wf[(c * 4 + 1) * 64 + l];
        v8h b2 = Wf[(c * 4 + 2) * 64 + l];
        v8h b3 = Wf[(c * 4 + 3) * 64 + l];
        acc[c] = __builtin_amdgcn_mfma_f32_16x16x32_f16(a0, b0, acc[c], 0, 0, 0);
        acc[c] = __builtin_amdgcn_mfma_f32_16x16x32_f16(a1, b1, acc[c], 0, 0, 0);
        acc[c] = __builtin_amdgcn_mfma_f32_16x16x32_f16(a2, b2, acc[c], 0, 0, 0);
        acc[c] = __builtin_amdgcn_mfma_f32_16x16x32_f16(a3, b3, acc[c], 0, 0, 0);
    }
#pragma unroll
    for (int reg = 0; reg < 4; ++reg) {
        int gr = rowbase + rb + quad * 4 + reg;
        if (gr < n) {
            float dn = dinv[gr];
#pragma unroll
            for (int c = 0; c < 8; ++c) {
                float z = acc[c][reg] + bias[c * 16 + nn];
                if (!finalLayer) z = fmaxf(z, 0.f) * dn;
                Out[(size_t)gr * 128 + c * 16 + nn] = __float2half_rn(z);
            }
        }
    }
}

// ---------------- edge decoder over fp16 X ----------------
__global__ __launch_bounds__(256) void decoder_h(const __half* __restrict__ X,
                                                 const int* __restrict__ eli,
                                                 float* __restrict__ out, int EL) {
    int e = blockIdx.x * 16 + (threadIdx.x >> 4);
    int lane = threadIdx.x & 15;
    if (e >= EL) return;
    int u = eli[e], v = eli[EL + e];
    uint4 ra = *(const uint4*)&X[(size_t)u * 128 + lane * 8];
    uint4 rb = *(const uint4*)&X[(size_t)v * 128 + lane * 8];
    const __half2* ha = (const __half2*)&ra;
    const __half2* hb = (const __half2*)&rb;
    float d = 0.f;
#pragma unroll
    for (int j = 0; j < 4; ++j) {
        float2 fa = __half22float2(ha[j]);
        float2 fb = __half22float2(hb[j]);
        d += fa.x * fb.x + fa.y * fb.y;
    }
#pragma unroll
    for (int off = 8; off > 0; off >>= 1) d += __shfl_xor(d, off);
    if (lane == 0) out[e] = d;
}

extern "C" void kernel_launch(void* const* d_in, const int* in_sizes, int n_in,
                              void* d_out, int out_size, void* d_ws, size_t ws_size,
                              hipStream_t stream) {
    const float* x0 = (const float*)d_in[0];
    const float* W1 = (const float*)d_in[1];
    const float* b1 = (const float*)d_in[2];
    const float* W2 = (const float*)d_in[3];
    const float* b2 = (const float*)d_in[4];
    const float* W3 = (const float*)d_in[5];
    const float* b3 = (const float*)d_in[6];
    const int* ei   = (const int*)d_in[7];
    const int* eli  = (const int*)d_in[8];
    float* out = (float*)d_out;

    const int D = 128;
    const int N  = in_sizes[0] / D;
    const int E  = in_sizes[7] / 2;
    const int EL = in_sizes[8] / 2;

    const int* src = ei;
    const int* dst = ei + E;

    // halfN: even, 2*halfN >= N, halfN/2 <= HWORDS  (N=50000 -> 25000)
    int halfN = (N + 1) / 2;
    halfN += (halfN & 1);
    int halfN2 = 2 * halfN;
    int chunk = (E + NB - 1) / NB;

    // -------- workspace carve-up (256B aligned) --------
    char* ws = (char*)d_ws;
    size_t off = 0;
    auto alloc = [&](size_t bytes) -> void* {
        off = (off + 255) & ~(size_t)255;
        void* p = ws + off;
        off += bytes;
        return p;
    };
    int*      cnt    = (int*)alloc((size_t)N * sizeof(int));
    int*      tmp    = (int*)alloc((size_t)N * sizeof(int));
    int*      bsum   = (int*)alloc(256 * sizeof(int));
    int*      rowptr = (int*)alloc((size_t)(N + 1) * sizeof(int));
    float*    dinv   = (float*)alloc((size_t)N * sizeof(float));
    int*      col    = (int*)alloc((size_t)(E + N) * sizeof(int));
    unsigned* hist32 = (unsigned*)alloc((size_t)NB * halfN * sizeof(unsigned));
    __half*   wfrag  = (__half*)alloc((size_t)3 * 16384 * sizeof(__half));
    __half*   xh0    = (__half*)alloc((size_t)N * D * sizeof(__half));   // fp16(x0)
    __half*   hbuf   = (__half*)alloc((size_t)N * D * sizeof(__half));   // h1 / x̃2
    __half*   xbuf   = (__half*)alloc((size_t)N * D * sizeof(__half));   // x̃1 / x3
    (void)ws_size;

    int nbN = (N + 255) / 256;
    int gemmGrid  = (N + 63) / 64;
    int fusedGrid = (N + 63) / 64;
    int aggGrid   = (N + 15) / 16;
    int nElem8    = N * D / 8;
    int convBlocks = (nElem8 + 255) / 256;

    // ---- D1: LDS histogram + x0->fp16 + W swizzle (no global atomics, no memset) ----
    hist_conv<<<NB + convBlocks + 192, 256, 0, stream>>>(dst, hist32, E, halfN, chunk,
                                                         x0, xh0, nElem8, convBlocks,
                                                         W1, W2, W3, wfrag);
    // ---- D2: layer-1 MFMA GEMM (unscaled) + scanA ----
    gemm1_scanA<<<gemmGrid + nbN, 256, 0, stream>>>(xh0, wfrag, hbuf, N, gemmGrid,
                                                    (const unsigned short*)hist32, halfN2,
                                                    cnt, tmp, bsum, N);
    // ---- D3: scanB + in-place vertical prefix of hist ----
    scanB<<<nbN, 256, 0, stream>>>(tmp, bsum, cnt, rowptr, dinv, col, N, nbN,
                                   (unsigned short*)hist32, halfN2);
    // ---- D4: scatter fill (LDS cursors, zero global atomics) ----
    scatter_fill<<<NB, 256, 0, stream>>>(src, dst, hist32, rowptr, col, E, halfN, chunk);

    // ---- layer 1: agg over unscaled h1, emits prescaled x̃1 ----
    agg_h<<<aggGrid, 256, 0, stream>>>(hbuf, dinv, rowptr, col, b1, xbuf, N);
    // ---- layer 2: fused aggregate-first + MFMA ----
    agg_gemm<<<fusedGrid, 256, 0, stream>>>(xbuf, dinv, rowptr, col, wfrag + 16384, b2, hbuf, N, 0);
    // ---- layer 3: fused, emits final x3 ----
    agg_gemm<<<fusedGrid, 256, 0, stream>>>(hbuf, dinv, rowptr, col, wfrag + 2 * 16384, b3, xbuf, N, 1);

    // ---- decoder ----
    decoder_h<<<(EL + 15) / 16, 256, 0, stream>>>(xbuf, eli, out, EL);
}

// Round 17
// 275.341 us; speedup vs baseline: 1.1447x; 1.1447x over previous
//
#include <hip/hip_runtime.h>
#include <hip/hip_bf16.h>
#include <hip/hip_fp16.h>

typedef _Float16 v8h __attribute__((ext_vector_type(8)));
typedef float v4f __attribute__((ext_vector_type(4)));

// ---------------- D1: x0->fp16 convert + W1/W2/W3 frag swizzle + degree/rank atomic pass ----------------
// Blocks [0, convBlocks): Xh = fp16(x0), 8 elems/thread (trivial bandwidth work).
// Blocks [convBlocks, +192): repack W1,W2,W3 (fp32) into fp16 MFMA B-fragment order:
//   wfrag[w][((c*4+s)*64 + quad*16 + n)*8 + j] = W[k=s*32+quad*8+j][c*16+n]
// Blocks [convBlocks+192, ...): rank[e] = atomicAdd(&cnt[dst[e]],1), 4 edges/thread —
// the ~45 µs coherent-RMW floor; conv/swizzle hide under it (m114 pipe overlap).
__global__ __launch_bounds__(256) void conv_swz_deg(const float* __restrict__ X0,
                                                    __half* __restrict__ Xh, int nElem8,
                                                    int convBlocks,
                                                    const float* __restrict__ W1,
                                                    const float* __restrict__ W2,
                                                    const float* __restrict__ W3,
                                                    __half* __restrict__ wfrag,
                                                    const int* __restrict__ dst,
                                                    int* __restrict__ cnt,
                                                    int* __restrict__ rank, int E) {
    int tid = threadIdx.x;
    if (blockIdx.x < convBlocks) {
        int i = blockIdx.x * 256 + tid;
        if (i < nElem8) {
            float4 v0 = ((const float4*)X0)[i * 2];
            float4 v1 = ((const float4*)X0)[i * 2 + 1];
            auto pk = [](float x, float y) { __half2 h = __floats2half2_rn(x, y); return *(unsigned int*)&h; };
            uint4 q = make_uint4(pk(v0.x, v0.y), pk(v0.z, v0.w), pk(v1.x, v1.y), pk(v1.z, v1.w));
            ((uint4*)Xh)[i] = q;
        }
        return;
    }
    int bb = blockIdx.x - convBlocks;
    if (bb < 192) {
        int o = bb * 256 + tid;              // 3*16384 elements
        int w = o >> 14, r = o & 16383;
        const float* Ws = (w == 0) ? W1 : (w == 1) ? W2 : W3;
        int k = r >> 7, ncol = r & 127;
        int c = ncol >> 4, nl = ncol & 15;
        int s = k >> 5, quad = (k >> 3) & 3, j = k & 7;
        int di = ((c * 4 + s) * 64 + quad * 16 + nl) * 8 + j;
        wfrag[(size_t)w * 16384 + di] = __float2half_rn(Ws[r]);
        return;
    }
    int base = (bb - 192) * 1024 + tid * 4;
    if (base + 3 < E) {
        int d0 = dst[base], d1 = dst[base + 1], d2 = dst[base + 2], d3 = dst[base + 3];
        int r0 = atomicAdd(&cnt[d0], 1);
        int r1 = atomicAdd(&cnt[d1], 1);
        int r2 = atomicAdd(&cnt[d2], 1);
        int r3 = atomicAdd(&cnt[d3], 1);
        rank[base] = r0; rank[base + 1] = r1; rank[base + 2] = r2; rank[base + 3] = r3;
    } else {
        for (int e = base; e < E; ++e) rank[e] = atomicAdd(&cnt[dst[e]], 1);
    }
}

// ---------------- scanA: per-block inclusive scan of (cnt[i]+1) ----------------
__global__ void scanA(const int* __restrict__ cnt, int* __restrict__ tmp,
                      int* __restrict__ bsum, int n) {
    __shared__ int s[256];
    int i = blockIdx.x * 256 + threadIdx.x;
    int v = (i < n) ? (cnt[i] + 1) : 0;
    s[threadIdx.x] = v;
    __syncthreads();
    for (int off = 1; off < 256; off <<= 1) {
        int x = (threadIdx.x >= off) ? s[threadIdx.x - off] : 0;
        __syncthreads();
        s[threadIdx.x] += x;
        __syncthreads();
    }
    if (i < n) tmp[i] = s[threadIdx.x];
    if (threadIdx.x == 255) bsum[blockIdx.x] = s[255];
}

// ---------------- scanB: redundant partial-scan + apply + dinv + self-loop ----------------
__global__ void scanB(const int* __restrict__ tmp, const int* __restrict__ bsum,
                      const int* __restrict__ cnt, int* __restrict__ rowptr,
                      float* __restrict__ dinv, int* __restrict__ col, int n, int nb) {
    __shared__ int p[256];
    int t = threadIdx.x;
    p[t] = (t < nb) ? bsum[t] : 0;
    __syncthreads();
    for (int off = 1; off < 256; off <<= 1) {
        int x = (t >= off) ? p[t - off] : 0;
        __syncthreads();
        p[t] += x;
        __syncthreads();
    }
    int prefix = (blockIdx.x == 0) ? 0 : p[blockIdx.x - 1];
    int i = blockIdx.x * 256 + t;
    if (i < n) {
        int inc = tmp[i] + prefix;
        rowptr[i + 1] = inc;
        int c1 = cnt[i] + 1;
        dinv[i] = rsqrtf((float)c1);
        col[inc - c1] = i;                     // self-loop occupies slot 0 of row i
        if (i == 0) rowptr[0] = 0;
    }
}

// ---------------- atomic-free CSR fill: col[rowptr[d]+1+rank[e]] = src[e] ----------------
__global__ __launch_bounds__(256) void fill4(const int* __restrict__ src,
                                             const int* __restrict__ dst,
                                             const int* __restrict__ rank,
                                             const int* __restrict__ rowptr,
                                             int* __restrict__ col, int E) {
    int base = blockIdx.x * 1024 + threadIdx.x * 4;
    if (base + 3 < E) {
        int d0 = dst[base], d1 = dst[base + 1], d2 = dst[base + 2], d3 = dst[base + 3];
        int s0 = src[base], s1 = src[base + 1], s2 = src[base + 2], s3 = src[base + 3];
        int r0 = rank[base], r1 = rank[base + 1], r2 = rank[base + 2], r3 = rank[base + 3];
        col[rowptr[d0] + 1 + r0] = s0;
        col[rowptr[d1] + 1 + r1] = s1;
        col[rowptr[d2] + 1 + r2] = s2;
        col[rowptr[d3] + 1 + r3] = s3;
    } else {
        for (int e = base; e < E; ++e)
            col[rowptr[dst[e]] + 1 + rank[e]] = src[e];
    }
}

// ---------------- FUSED layer: Out = post( (dinv ⊙ Â·X) @ W + b ) ----------------
// Aggregate-first (A(XW)=(AX)W).  Block = 64 rows.  Phase A: 4 passes x (16 nodes x
// 16 lanes) gather y = dinv_n * Σ w_s·X[s] into 17KB LDS tile (fp16); gdinv=1: w_s =
// dinv[s] (X unscaled, layer 1); gdinv=0: w_s = 1 (X pre-scaled).  Phase B: per-wave
// 16-row MFMA vs pre-swizzled wfrag (no LDS for W, coalesced 1KB loads).
// finalLayer=0: out = dinv ⊙ relu(z) (next x̃);  =1: out = z (decoder input).
__global__ __launch_bounds__(256) void agg_gemm(const __half* __restrict__ Xs,
                                                const float* __restrict__ dinv,
                                                const int* __restrict__ rowptr,
                                                const int* __restrict__ col,
                                                const __half* __restrict__ wfrag,
                                                const float* __restrict__ bias,
                                                __half* __restrict__ Out,
                                                int n, int finalLayer, int gdinv) {
    __shared__ __align__(16) _Float16 y[64][136];   // +8 halfs pad
    int tid = threadIdx.x;
    int rowbase = blockIdx.x * 64;
    // ---- phase A ----
    {
        int sub = tid >> 4;               // node-in-group 0..15
        int t = (tid & 15) * 8;           // dim offset (halfs)
        for (int g = 0; g < 4; ++g) {
            int rr = g * 16 + sub;
            int node = rowbase + rr;
            float a[8] = {};
            if (node < n) {
                int beg = rowptr[node], end = rowptr[node + 1];
                int k = beg;
                for (; k + 4 <= end; k += 4) {
                    int s0 = col[k], s1 = col[k + 1], s2 = col[k + 2], s3 = col[k + 3];
                    float w0 = 1.f, w1 = 1.f, w2 = 1.f, w3 = 1.f;
                    if (gdinv) { w0 = dinv[s0]; w1 = dinv[s1]; w2 = dinv[s2]; w3 = dinv[s3]; }
                    uint4 r0 = *(const uint4*)&Xs[(size_t)s0 * 128 + t];
                    uint4 r1 = *(const uint4*)&Xs[(size_t)s1 * 128 + t];
                    uint4 r2 = *(const uint4*)&Xs[(size_t)s2 * 128 + t];
                    uint4 r3 = *(const uint4*)&Xs[(size_t)s3 * 128 + t];
                    const __half2* h0 = (const __half2*)&r0;
                    const __half2* h1 = (const __half2*)&r1;
                    const __half2* h2 = (const __half2*)&r2;
                    const __half2* h3 = (const __half2*)&r3;
#pragma unroll
                    for (int m = 0; m < 4; ++m) {
                        float2 f0 = __half22float2(h0[m]);
                        float2 f1 = __half22float2(h1[m]);
                        float2 f2 = __half22float2(h2[m]);
                        float2 f3 = __half22float2(h3[m]);
                        a[2 * m]     += f0.x * w0 + f1.x * w1 + f2.x * w2 + f3.x * w3;
                        a[2 * m + 1] += f0.y * w0 + f1.y * w1 + f2.y * w2 + f3.y * w3;
                    }
                }
                for (; k < end; ++k) {
                    int s0 = col[k];
                    float w0 = gdinv ? dinv[s0] : 1.f;
                    uint4 r0 = *(const uint4*)&Xs[(size_t)s0 * 128 + t];
                    const __half2* h0 = (const __half2*)&r0;
#pragma unroll
                    for (int m = 0; m < 4; ++m) {
                        float2 f0 = __half22float2(h0[m]);
                        a[2 * m] += f0.x * w0;
                        a[2 * m + 1] += f0.y * w0;
                    }
                }
                float dn = dinv[node];
#pragma unroll
                for (int m = 0; m < 8; ++m) a[m] *= dn;
            }
            v8h yv;
#pragma unroll
            for (int m = 0; m < 8; ++m) yv[m] = (_Float16)a[m];
            *(v8h*)&y[rr][t] = yv;
        }
    }
    __syncthreads();
    // ---- phase B: 4 waves x 16 rows, mfma_f32_16x16x32_f16 ----
    int l = tid & 63;
    int wid = tid >> 6;
    int rb = wid * 16;
    int quad = l >> 4;
    int nn = l & 15;
    v8h a0 = *(const v8h*)&y[rb + nn][0 * 32 + quad * 8];
    v8h a1 = *(const v8h*)&y[rb + nn][1 * 32 + quad * 8];
    v8h a2 = *(const v8h*)&y[rb + nn][2 * 32 + quad * 8];
    v8h a3 = *(const v8h*)&y[rb + nn][3 * 32 + quad * 8];
    const v8h* Wf = (const v8h*)wfrag;
    v4f acc[8] = {};
#pragma unroll
    for (int c = 0; c < 8; ++c) {
        v8h b0 = Wf[(c * 4 + 0) * 64 + l];
        v8h b1 = Wf[(c * 4 + 1) * 64 + l];
        v8h b2 = Wf[(c * 4 + 2) * 64 + l];
        v8h b3 = Wf[(c * 4 + 3) * 64 + l];
        acc[c] = __builtin_amdgcn_mfma_f32_16x16x32_f16(a0, b0, acc[c], 0, 0, 0);
        acc[c] = __builtin_amdgcn_mfma_f32_16x16x32_f16(a1, b1, acc[c], 0, 0, 0);
        acc[c] = __builtin_amdgcn_mfma_f32_16x16x32_f16(a2, b2, acc[c], 0, 0, 0);
        acc[c] = __builtin_amdgcn_mfma_f32_16x16x32_f16(a3, b3, acc[c], 0, 0, 0);
    }
#pragma unroll
    for (int reg = 0; reg < 4; ++reg) {
        int gr = rowbase + rb + quad * 4 + reg;
        if (gr < n) {
            float dn = dinv[gr];
#pragma unroll
            for (int c = 0; c < 8; ++c) {
                float z = acc[c][reg] + bias[c * 16 + nn];
                if (!finalLayer) z = fmaxf(z, 0.f) * dn;
                Out[(size_t)gr * 128 + c * 16 + nn] = __float2half_rn(z);
            }
        }
    }
}

// ---------------- edge decoder over fp16 X: out[e] = dot(X[u], X[v]) ----------------
__global__ __launch_bounds__(256) void decoder_h(const __half* __restrict__ X,
                                                 const int* __restrict__ eli,
                                                 float* __restrict__ out, int EL) {
    int e = blockIdx.x * 16 + (threadIdx.x >> 4);
    int lane = threadIdx.x & 15;
    if (e >= EL) return;
    int u = eli[e], v = eli[EL + e];
    uint4 ra = *(const uint4*)&X[(size_t)u * 128 + lane * 8];
    uint4 rb = *(const uint4*)&X[(size_t)v * 128 + lane * 8];
    const __half2* ha = (const __half2*)&ra;
    const __half2* hb = (const __half2*)&rb;
    float d = 0.f;
#pragma unroll
    for (int j = 0; j < 4; ++j) {
        float2 fa = __half22float2(ha[j]);
        float2 fb = __half22float2(hb[j]);
        d += fa.x * fb.x + fa.y * fb.y;
    }
#pragma unroll
    for (int off = 8; off > 0; off >>= 1) d += __shfl_xor(d, off);
    if (lane == 0) out[e] = d;
}

extern "C" void kernel_launch(void* const* d_in, const int* in_sizes, int n_in,
                              void* d_out, int out_size, void* d_ws, size_t ws_size,
                              hipStream_t stream) {
    const float* x0 = (const float*)d_in[0];
    const float* W1 = (const float*)d_in[1];
    const float* b1 = (const float*)d_in[2];
    const float* W2 = (const float*)d_in[3];
    const float* b2 = (const float*)d_in[4];
    const float* W3 = (const float*)d_in[5];
    const float* b3 = (const float*)d_in[6];
    const int* ei   = (const int*)d_in[7];
    const int* eli  = (const int*)d_in[8];
    float* out = (float*)d_out;

    const int D = 128;
    const int N  = in_sizes[0] / D;
    const int E  = in_sizes[7] / 2;
    const int EL = in_sizes[8] / 2;

    const int* src = ei;
    const int* dst = ei + E;

    // -------- workspace carve-up (256B aligned) --------
    char* ws = (char*)d_ws;
    size_t off = 0;
    auto alloc = [&](size_t bytes) -> void* {
        off = (off + 255) & ~(size_t)255;
        void* p = ws + off;
        off += bytes;
        return p;
    };
    int*    cnt    = (int*)alloc((size_t)N * sizeof(int));
    int*    tmp    = (int*)alloc((size_t)N * sizeof(int));
    int*    bsum   = (int*)alloc(256 * sizeof(int));
    int*    rowptr = (int*)alloc((size_t)(N + 1) * sizeof(int));
    float*  dinv   = (float*)alloc((size_t)N * sizeof(float));
    int*    rank   = (int*)alloc((size_t)E * sizeof(int));
    int*    col    = (int*)alloc((size_t)(E + N) * sizeof(int));
    __half* wfrag  = (__half*)alloc((size_t)3 * 16384 * sizeof(__half));
    __half* xh0    = (__half*)alloc((size_t)N * D * sizeof(__half));   // fp16(x0)
    __half* hbuf   = (__half*)alloc((size_t)N * D * sizeof(__half));   // x̃1 / x3
    __half* xbuf   = (__half*)alloc((size_t)N * D * sizeof(__half));   // x̃2
    (void)ws_size;

    hipMemsetAsync(cnt, 0, (size_t)N * sizeof(int), stream);

    int nbN = (N + 255) / 256;
    int nbE4 = (E + 1023) / 1024;
    int fusedGrid = (N + 63) / 64;
    int nElem8    = N * D / 8;
    int convBlocks = (nElem8 + 255) / 256;

    // ---- D1: x0->fp16 + W swizzle + degree/rank atomic pass (conv/swz hide under atomics) ----
    conv_swz_deg<<<convBlocks + 192 + nbE4, 256, 0, stream>>>(x0, xh0, nElem8, convBlocks,
                                                              W1, W2, W3, wfrag,
                                                              dst, cnt, rank, E);

    // ---- scan -> rowptr/dinv/self-loops; atomic-free fill ----
    scanA<<<nbN, 256, 0, stream>>>(cnt, tmp, bsum, N);
    scanB<<<nbN, 256, 0, stream>>>(tmp, bsum, cnt, rowptr, dinv, col, N, nbN);
    fill4<<<nbE4, 256, 0, stream>>>(src, dst, rank, rowptr, col, E);

    // ---- layer 1: fused agg(gdinv per-edge)+MFMA over fp16(x0), emits prescaled x̃1 ----
    agg_gemm<<<fusedGrid, 256, 0, stream>>>(xh0, dinv, rowptr, col, wfrag, b1, hbuf, N, 0, 1);
    // ---- layer 2: fused, emits prescaled x̃2 ----
    agg_gemm<<<fusedGrid, 256, 0, stream>>>(hbuf, dinv, rowptr, col, wfrag + 16384, b2, xbuf, N, 0, 0);
    // ---- layer 3: fused, emits final x3 ----
    agg_gemm<<<fusedGrid, 256, 0, stream>>>(xbuf, dinv, rowptr, col, wfrag + 2 * 16384, b3, hbuf, N, 1, 0);

    // ---- decoder ----
    decoder_h<<<(EL + 15) / 16, 256, 0, stream>>>(hbuf, eli, out, EL);
}